// Round 15
// baseline (490.214 us; speedup 1.0000x reference)
//
#include <hip/hip_runtime.h>

#define L_SEQ 4096
#define NSTEP 2047
#define ST_W  (-0.000625f)   // -LR * (2/H) = -0.01/16

typedef float f32x4 __attribute__((ext_vector_type(4)));

// ws layout (bytes):
//  [0,      8192)   table  64x32 f32
//  [8192,  24576)   G      64x64 f32
//  [24576, 26624)   Z0     64x8  f32
//  [26624, 26628)   wacc   f32
//  [28672, 94208)   flags  256 rows x 64 words (bit j of word c = wr_{32c+j})

// ---------------------------------------------------------------------------
// Cross-lane reduction helpers (VALU pipe). Layout: i = lane&7, g = lane>>3.
// (Prologue/epilogue only; main loop inlines them in the monolithic block.)
// ---------------------------------------------------------------------------
__device__ __forceinline__ void redi4(float& a, float& b, float& c, float& d) {
    asm volatile(
        "s_nop 1\n\t"
        "v_add_f32_dpp %0, %0, %0 quad_perm:[1,0,3,2] row_mask:0xf bank_mask:0xf bound_ctrl:0\n\t"
        "v_add_f32_dpp %1, %1, %1 quad_perm:[1,0,3,2] row_mask:0xf bank_mask:0xf bound_ctrl:0\n\t"
        "v_add_f32_dpp %2, %2, %2 quad_perm:[1,0,3,2] row_mask:0xf bank_mask:0xf bound_ctrl:0\n\t"
        "v_add_f32_dpp %3, %3, %3 quad_perm:[1,0,3,2] row_mask:0xf bank_mask:0xf bound_ctrl:0\n\t"
        "v_add_f32_dpp %0, %0, %0 quad_perm:[2,3,0,1] row_mask:0xf bank_mask:0xf bound_ctrl:0\n\t"
        "v_add_f32_dpp %1, %1, %1 quad_perm:[2,3,0,1] row_mask:0xf bank_mask:0xf bound_ctrl:0\n\t"
        "v_add_f32_dpp %2, %2, %2 quad_perm:[2,3,0,1] row_mask:0xf bank_mask:0xf bound_ctrl:0\n\t"
        "v_add_f32_dpp %3, %3, %3 quad_perm:[2,3,0,1] row_mask:0xf bank_mask:0xf bound_ctrl:0\n\t"
        "v_add_f32_dpp %0, %0, %0 row_half_mirror row_mask:0xf bank_mask:0xf bound_ctrl:0\n\t"
        "v_add_f32_dpp %1, %1, %1 row_half_mirror row_mask:0xf bank_mask:0xf bound_ctrl:0\n\t"
        "v_add_f32_dpp %2, %2, %2 row_half_mirror row_mask:0xf bank_mask:0xf bound_ctrl:0\n\t"
        "v_add_f32_dpp %3, %3, %3 row_half_mirror row_mask:0xf bank_mask:0xf bound_ctrl:0"
        : "+v"(a), "+v"(b), "+v"(c), "+v"(d));
}

__device__ __forceinline__ float redg1(float x) {
    float t;
    asm volatile(
        "s_nop 1\n\t"
        "v_add_f32_dpp %0, %0, %0 row_ror:8 row_mask:0xf bank_mask:0xf bound_ctrl:0\n\t"
        "v_mov_b32 %1, %0\n\t"
        "s_nop 1\n\t"
        "v_permlane16_swap_b32 %1, %0\n\t"
        "v_add_f32 %0, %0, %1\n\t"
        "v_mov_b32 %1, %0\n\t"
        "s_nop 1\n\t"
        "v_permlane32_swap_b32 %1, %0\n\t"
        "v_add_f32 %0, %0, %1"
        : "+v"(x), "=&v"(t));
    return x;
}

// select Z[r] among 8 regs; r wave-uniform (SGPR). SALU masks; ONE asm block.
__device__ __forceinline__ float sel8u(const float* Z, int r) {
    unsigned long long m0 = (r & 1) ? ~0ull : 0ull;
    unsigned long long m1 = (r & 2) ? ~0ull : 0ull;
    unsigned long long m2 = (r & 4) ? ~0ull : 0ull;
    float res, t0, t1, t2;
    asm("v_cndmask_b32 %1, %4, %5, %12\n\t"
        "v_cndmask_b32 %2, %6, %7, %12\n\t"
        "v_cndmask_b32 %3, %8, %9, %12\n\t"
        "v_cndmask_b32 %0, %10, %11, %12\n\t"
        "v_cndmask_b32 %1, %1, %2, %13\n\t"
        "v_cndmask_b32 %3, %3, %0, %13\n\t"
        "v_cndmask_b32 %0, %1, %3, %14"
        : "=&v"(res), "=&v"(t0), "=&v"(t1), "=&v"(t2)
        : "v"(Z[0]), "v"(Z[1]), "v"(Z[2]), "v"(Z[3]),
          "v"(Z[4]), "v"(Z[5]), "v"(Z[6]), "v"(Z[7]),
          "s"(m0), "s"(m1), "s"(m2));
    return res;
}

__device__ __forceinline__ float bperm_row(int tok, int i4, float v) {
    int addr = ((tok & 56) << 2) | i4;
    return __int_as_float(__builtin_amdgcn_ds_bpermute(addr, __float_as_int(v)));
}

__device__ __forceinline__ int rli(int x, int l) {
    return __builtin_amdgcn_readlane(x, l);
}

// ---------------------------------------------------------------------------
// Phase A+B1 fused: each block builds table+G in LDS, then its row's gates.
// Block 0 additionally stores table/G/Z0 to ws for the scan kernel.
// ---------------------------------------------------------------------------
__global__ __launch_bounds__(256) void flags_kernel(
    const int* __restrict__ seq, const float* __restrict__ embed,
    const float* __restrict__ ff1_w, const float* __restrict__ ff1_b,
    const float* __restrict__ ff2_w, const float* __restrict__ ff2_b,
    const float* __restrict__ ln_g, const float* __restrict__ ln_b,
    const float* __restrict__ fc1_w,
    float* __restrict__ table, float* __restrict__ G, float* __restrict__ Z0,
    unsigned int* __restrict__ flags, float* __restrict__ wacc)
{
    __shared__ float Gs[4096];
    __shared__ float tl[64][32];
    __shared__ float P[64][64];
    __shared__ int   kt[2048];
    __shared__ float Aa[2048];
    __shared__ float Ws[2048];
    __shared__ float red[256];
    const int tid = threadIdx.x, b = blockIdx.x;
    const int2* sp2 = reinterpret_cast<const int2*>(seq + b * L_SEQ);
    for (int j = tid; j < 2048; j += 256) kt[j] = sp2[j].x;

    if (tid < 64) {
        const int v = tid;
        float h[32], f[32];
#pragma unroll
        for (int j = 0; j < 32; ++j) { h[j] = embed[v * 32 + j]; f[j] = 0.f; }
        for (int k = 0; k < 64; ++k) {
            float z = ff1_b[k];
#pragma unroll
            for (int j = 0; j < 32; ++j) z += h[j] * ff1_w[k * 32 + j];
            z = fmaxf(z, 0.f);
#pragma unroll
            for (int j = 0; j < 32; ++j) f[j] += z * ff2_w[j * 64 + k];
        }
        float x[32], mu = 0.f;
#pragma unroll
        for (int j = 0; j < 32; ++j) { x[j] = h[j] + f[j] + ff2_b[j]; mu += x[j]; }
        mu *= (1.f / 32.f);
        float var = 0.f;
#pragma unroll
        for (int j = 0; j < 32; ++j) { float d = x[j] - mu; var += d * d; }
        var *= (1.f / 32.f);
        const float inv = rsqrtf(var + 1e-5f);
#pragma unroll
        for (int j = 0; j < 32; ++j) {
            float tv = ln_g[j] * (x[j] - mu) * inv + ln_b[j];
            tl[v][j] = tv;
            if (b == 0) table[v * 32 + j] = tv;
        }
    }
    __syncthreads();

    for (int idx = tid; idx < 4096; idx += 256) {
        const int v = idx >> 6, u = idx & 63;
        float acc = 0.f;
#pragma unroll
        for (int j = 0; j < 32; ++j) acc += tl[v][j] * tl[u][j];
        Gs[idx] = acc;
        if (b == 0) G[idx] = acc;
    }
    if (b == 0) {
        for (int idx = tid; idx < 512; idx += 256) {
            const int v = idx >> 3, i = idx & 7;
            float acc = 0.f;
#pragma unroll
            for (int j = 0; j < 32; ++j) acc += fc1_w[i * 32 + j] * tl[v][j];
            Z0[idx] = acc;
        }
    }
    __syncthreads();

    for (int idx = tid; idx < 4096; idx += 256) {
        const int c = idx >> 6, u = idx & 63;
        const int base = c * 32;
        float s = 0.f;
#pragma unroll 4
        for (int j = 0; j < 32; ++j) s += Gs[kt[base + j] * 64 + u];
        P[c][u] = s;
    }
    __syncthreads();
    if (tid < 64) {
        float acc = 0.f;
        for (int c = 0; c < 64; ++c) { float p = P[c][tid]; P[c][tid] = acc; acc += p; }
    }
    __syncthreads();
    for (int t = tid; t < NSTEP; t += 256) {
        const int c = t >> 5, base = c << 5;
        const int ktt = kt[t];
        float a = P[c][ktt];
        for (int s = base; s < t; ++s) a += Gs[kt[s] * 64 + ktt];
        Aa[t] = a;
        Ws[t] = 2.f * a + Gs[ktt * 65];
    }
    __syncthreads();
    float loc[8], tot = 0.f;
    const int base8 = tid * 8;
#pragma unroll
    for (int j = 0; j < 8; ++j) {
        float v = (base8 + j < NSTEP) ? Ws[base8 + j] : 0.f;
        loc[j] = tot; tot += v;
    }
    red[tid] = tot;
    __syncthreads();
    float run = tot;
    for (int off = 1; off < 256; off <<= 1) {
        float add = (tid >= off) ? red[tid - off] : 0.f;
        __syncthreads();
        run += add; red[tid] = run;
        __syncthreads();
    }
    const float excl = run - tot;
    __syncthreads();
#pragma unroll
    for (int j = 0; j < 8; ++j) {
        const int t = base8 + j;
        if (t < NSTEP) {
            const float u_t = excl + loc[j];
            const float tf = (float)t;
            const int ktt = kt[t];
            const float r = fmaf(tf * tf, Gs[ktt * 65] - 16.f, u_t)
                            - 2.f * tf * Aa[t];
            Ws[t] = (t == 0 || r > 0.f) ? 1.f : 0.f;
        }
    }
    __syncthreads();
    int cnt = 0;
    if (tid < 64) {
        unsigned int w = 0;
        for (int j = 0; j < 32; ++j) {
            const int t = tid * 32 + j;
            if (t < NSTEP && Ws[t] != 0.f) w |= 1u << j;
        }
        flags[b * 64 + tid] = w;
        cnt = __popc(w);
    }
    red[tid] = (float)cnt;
    __syncthreads();
    if (tid == 0) {
        float s = 0.f;
        for (int j = 0; j < 64; ++j) s += red[j];
        atomicAdd(wacc, s);
    }
}

// ---------------------------------------------------------------------------
// Phase B2: fast-weight scan. One wave per batch row, 256 blocks (1/CU).
// Loop body re-rolled to 8-step unroll (runtime sb-loop of 4) so the body
// (~8-10 KB) fits the 32 KB L1I; lane indices are runtime-uniform SGPRs.
// Monolithic per-step asm core unchanged from R14.
// ---------------------------------------------------------------------------
__global__ __launch_bounds__(64) void scan_kernel(
    const int* __restrict__ seq, const float* __restrict__ tableg,
    const float* __restrict__ Gg, const float* __restrict__ Z0g,
    const float* __restrict__ fc1_b, const float* __restrict__ fc2_w,
    const float* __restrict__ fc2_b, const float* __restrict__ out_w,
    const float* __restrict__ out_b, const unsigned int* __restrict__ flags,
    const float* __restrict__ wacc, float* __restrict__ out)
{
    __shared__ float Gs[4096];
    __shared__ float tabs[2048];
    __shared__ float ctx_s[32];
    const int b = blockIdx.x, tid = threadIdx.x;
    const int i = tid & 7, g = tid >> 3;
    const int l31 = tid & 31;
    const int i4 = i << 2;

    if (b == 0 && tid == 0) out[16384] = wacc[0] * (1.0f / 524032.0f);

    for (int idx = tid; idx < 4096; idx += 64) Gs[idx] = Gg[idx];
    for (int idx = tid; idx < 2048; idx += 64) tabs[idx] = tableg[idx];
    __syncthreads();
    const f32x4* tab4 = reinterpret_cast<const f32x4*>(tabs);

    // --- state ---
    float Zr[8];
#pragma unroll
    for (int r = 0; r < 8; ++r) Zr[r] = Z0g[(8 * g + r) * 8 + i];
    float b1 = fc1_b[i];
    float W2r0 = fc2_w[(4 * g + 0) * 8 + i];
    float W2r1 = fc2_w[(4 * g + 1) * 8 + i];
    float W2r2 = fc2_w[(4 * g + 2) * 8 + i];
    float W2r3 = fc2_w[(4 * g + 3) * 8 + i];
    float b2x = fc2_b[4 * g + 0], b2y = fc2_b[4 * g + 1];
    float b2z = fc2_b[4 * g + 2], b2w = fc2_b[4 * g + 3];

    const int2* sp2 = reinterpret_cast<const int2*>(seq + b * L_SEQ);
    const unsigned int fwv = flags[b * 64 + tid];   // lane l holds flag word l

    int2 cbA = sp2[l31];          // chunk c
    int2 cbB = sp2[32 + l31];     // chunk c+1
    int2 cbC;                     // chunk c+2 (prefetched per chunk)

    // --- prologue (t = 0) ---
    int kS = rli(cbA.x, 0);
    int vS = rli(cbA.y, 0);
    const f32x4* gp0 = reinterpret_cast<const f32x4*>(Gs + kS * 64 + 8 * g);
    f32x4 GaC = gp0[0], GbC = gp0[1];
    f32x4 vc0 = tab4[vS * 8 + g];
    float yb = bperm_row(kS, i4, sel8u(Zr, kS & 7)) + b1;
    float es0 = b2x - vc0.x, es1 = b2y - vc0.y;
    float es2 = b2z - vc0.z, es3 = b2w - vc0.w;
    float c_prev = 0.f, gB1c = 0.f;

    for (int c = 0; c < 64; ++c) {
        const unsigned int fw = (unsigned int)rli((int)fwv, c);
        {   // prefetch chunk c+2 tokens (1 global load / 32 steps)
            int c2 = c + 2; if (c2 > 63) c2 = 63;
            cbC = sp2[c2 * 32 + l31];
        }
        for (int sb = 0; sb < 4; ++sb) {        // runtime: body ~8-10 KB
            const int lb = sb * 8;
#pragma unroll
            for (int j = 0; j < 8; ++j) {
                // token for step t+1: lane = lb+j+1 (runtime-uniform SGPR idx)
                int kN, vN;
                if (j < 7) {                     // lane <= 31 guaranteed
                    kN = rli(cbA.x, lb + j + 1);
                    vN = rli(cbA.y, lb + j + 1);
                } else {                         // lane = lb+8 (32 when sb==3)
                    const int lw = (lb + 8) & 31;
                    int ka = rli(cbA.x, lw), kb2 = rli(cbB.x, lw);
                    int va = rli(cbA.y, lw), vb2 = rli(cbB.y, lw);
                    const bool hi = (sb == 3);
                    kN = hi ? kb2 : ka;
                    vN = hi ? vb2 : va;
                }
                const float st = ((fw >> (lb + j)) & 1u) ? ST_W : 0.f;

                // issue ALL DS for step t+1 (plain C; consumed after block)
                float ynv = bperm_row(kN, i4, sel8u(Zr, kN & 7));
                const f32x4* gpn =
                    reinterpret_cast<const f32x4*>(Gs + kN * 64 + 8 * g);
                f32x4 GaN = gpn[0], GbN = gpn[1];
                f32x4 vcN = tab4[vN * 8 + g];
                float gbN = Gs[kS * 64 + kN];    // G[k_t][k_{t+1}]

                // --- monolithic step-t core (inputs >= 1 iteration old) ---
                float aa, p0, p1, p2, p3, qq, tt, tu;
                asm volatile(
                    "v_fma_f32 %[tt], %[cp], %[gB], %[yb]\n\t"
                    "v_max_f32 %[aa], 0, %[tt]\n\t"
                    "v_mul_f32 %[p0], %[w0], %[aa]\n\t"
                    "v_mul_f32 %[p1], %[w1], %[aa]\n\t"
                    "v_mul_f32 %[p2], %[w2], %[aa]\n\t"
                    "v_mul_f32 %[p3], %[w3], %[aa]\n\t"
                    "s_nop 1\n\t"
                    "v_add_f32_dpp %[p0], %[p0], %[p0] quad_perm:[1,0,3,2] row_mask:0xf bank_mask:0xf bound_ctrl:0\n\t"
                    "v_add_f32_dpp %[p1], %[p1], %[p1] quad_perm:[1,0,3,2] row_mask:0xf bank_mask:0xf bound_ctrl:0\n\t"
                    "v_add_f32_dpp %[p2], %[p2], %[p2] quad_perm:[1,0,3,2] row_mask:0xf bank_mask:0xf bound_ctrl:0\n\t"
                    "v_add_f32_dpp %[p3], %[p3], %[p3] quad_perm:[1,0,3,2] row_mask:0xf bank_mask:0xf bound_ctrl:0\n\t"
                    "v_add_f32_dpp %[p0], %[p0], %[p0] quad_perm:[2,3,0,1] row_mask:0xf bank_mask:0xf bound_ctrl:0\n\t"
                    "v_add_f32_dpp %[p1], %[p1], %[p1] quad_perm:[2,3,0,1] row_mask:0xf bank_mask:0xf bound_ctrl:0\n\t"
                    "v_add_f32_dpp %[p2], %[p2], %[p2] quad_perm:[2,3,0,1] row_mask:0xf bank_mask:0xf bound_ctrl:0\n\t"
                    "v_add_f32_dpp %[p3], %[p3], %[p3] quad_perm:[2,3,0,1] row_mask:0xf bank_mask:0xf bound_ctrl:0\n\t"
                    "v_add_f32_dpp %[p0], %[p0], %[p0] row_half_mirror row_mask:0xf bank_mask:0xf bound_ctrl:0\n\t"
                    "v_add_f32_dpp %[p1], %[p1], %[p1] row_half_mirror row_mask:0xf bank_mask:0xf bound_ctrl:0\n\t"
                    "v_add_f32_dpp %[p2], %[p2], %[p2] row_half_mirror row_mask:0xf bank_mask:0xf bound_ctrl:0\n\t"
                    "v_add_f32_dpp %[p3], %[p3], %[p3] row_half_mirror row_mask:0xf bank_mask:0xf bound_ctrl:0\n\t"
                    "v_add_f32 %[p0], %[p0], %[e0]\n\t"
                    "v_add_f32 %[p1], %[p1], %[e1]\n\t"
                    "v_add_f32 %[p2], %[p2], %[e2]\n\t"
                    "v_add_f32 %[p3], %[p3], %[e3]\n\t"
                    "v_mul_f32 %[qq], %[w0], %[p0]\n\t"
                    "v_fma_f32 %[qq], %[w1], %[p1], %[qq]\n\t"
                    "v_fma_f32 %[qq], %[w2], %[p2], %[qq]\n\t"
                    "v_fma_f32 %[qq], %[w3], %[p3], %[qq]\n\t"
                    "s_nop 1\n\t"
                    "v_add_f32_dpp %[qq], %[qq], %[qq] row_ror:8 row_mask:0xf bank_mask:0xf bound_ctrl:0\n\t"
                    "v_mov_b32 %[tu], %[qq]\n\t"
                    "s_nop 1\n\t"
                    "v_permlane16_swap_b32 %[tu], %[qq]\n\t"
                    "v_add_f32 %[qq], %[qq], %[tu]\n\t"
                    "v_mov_b32 %[tu], %[qq]\n\t"
                    "s_nop 1\n\t"
                    "v_permlane32_swap_b32 %[tu], %[qq]\n\t"
                    "v_add_f32 %[qq], %[qq], %[tu]\n\t"
                    "v_mul_f32 %[tu], %[st], %[qq]\n\t"
                    "v_cmp_lt_f32 vcc, 0, %[tt]\n\t"
                    "v_cndmask_b32 %[tu], 0, %[tu], vcc\n\t"
                    "v_mul_f32 %[p0], %[st], %[p0]\n\t"
                    "v_mul_f32 %[p1], %[st], %[p1]\n\t"
                    "v_mul_f32 %[p2], %[st], %[p2]\n\t"
                    "v_mul_f32 %[p3], %[st], %[p3]\n\t"
                    "v_fma_f32 %[w0], %[p0], %[aa], %[w0]\n\t"
                    "v_fma_f32 %[w1], %[p1], %[aa], %[w1]\n\t"
                    "v_fma_f32 %[w2], %[p2], %[aa], %[w2]\n\t"
                    "v_fma_f32 %[w3], %[p3], %[aa], %[w3]\n\t"
                    "v_add_f32 %[c0], %[c0], %[p0]\n\t"
                    "v_add_f32 %[c1], %[c1], %[p1]\n\t"
                    "v_add_f32 %[c2], %[c2], %[p2]\n\t"
                    "v_add_f32 %[c3], %[c3], %[p3]\n\t"
                    "v_fma_f32 %[z0], %[tu], %[ga0], %[z0]\n\t"
                    "v_fma_f32 %[z1], %[tu], %[ga1], %[z1]\n\t"
                    "v_fma_f32 %[z2], %[tu], %[ga2], %[z2]\n\t"
                    "v_fma_f32 %[z3], %[tu], %[ga3], %[z3]\n\t"
                    "v_fma_f32 %[z4], %[tu], %[gb0], %[z4]\n\t"
                    "v_fma_f32 %[z5], %[tu], %[gb1], %[z5]\n\t"
                    "v_fma_f32 %[z6], %[tu], %[gb2], %[z6]\n\t"
                    "v_fma_f32 %[z7], %[tu], %[gb3], %[z7]\n\t"
                    "v_add_f32 %[bb], %[bb], %[tu]"
                    : [z0]"+v"(Zr[0]), [z1]"+v"(Zr[1]), [z2]"+v"(Zr[2]),
                      [z3]"+v"(Zr[3]), [z4]"+v"(Zr[4]), [z5]"+v"(Zr[5]),
                      [z6]"+v"(Zr[6]), [z7]"+v"(Zr[7]),
                      [w0]"+v"(W2r0), [w1]"+v"(W2r1), [w2]"+v"(W2r2), [w3]"+v"(W2r3),
                      [c0]"+v"(b2x), [c1]"+v"(b2y), [c2]"+v"(b2z), [c3]"+v"(b2w),
                      [bb]"+v"(b1),
                      [aa]"=&v"(aa), [p0]"=&v"(p0), [p1]"=&v"(p1), [p2]"=&v"(p2),
                      [p3]"=&v"(p3), [qq]"=&v"(qq), [tt]"=&v"(tt), [tu]"=&v"(tu)
                    : [yb]"v"(yb), [cp]"v"(c_prev), [gB]"v"(gB1c),
                      [e0]"v"(es0), [e1]"v"(es1), [e2]"v"(es2), [e3]"v"(es3),
                      [ga0]"v"(GaC.x), [ga1]"v"(GaC.y), [ga2]"v"(GaC.z), [ga3]"v"(GaC.w),
                      [gb0]"v"(GbC.x), [gb1]"v"(GbC.y), [gb2]"v"(GbC.z), [gb3]"v"(GbC.w),
                      [st]"s"(st)
                    : "vcc");

                // --- post-block C (consumes THIS iter's DS) ---
                yb = ynv + b1;                   // b1 post-update fold
                es0 = b2x - vcN.x; es1 = b2y - vcN.y;
                es2 = b2z - vcN.z; es3 = b2w - vcN.w;
                c_prev = tu; gB1c = gbN;
                GaC = GaN; GbC = GbN; kS = kN;
            }
        }
        cbA = cbB; cbB = cbC;
    }

    // --- query/context (state = after the 2047 real steps) ---
    const int tq = seq[b * L_SEQ + (L_SEQ - 1)];
    float yq = bperm_row(tq, i4, sel8u(Zr, tq & 7));
    const float zq = yq + b1;
    const float aq = fmaxf(zq, 0.f);
    float c0 = W2r0 * aq, c1 = W2r1 * aq, c2 = W2r2 * aq, c3 = W2r3 * aq;
    redi4(c0, c1, c2, c3);
    if (i == 0) {
        ctx_s[4 * g + 0] = c0 + b2x;
        ctx_s[4 * g + 1] = c1 + b2y;
        ctx_s[4 * g + 2] = c2 + b2z;
        ctx_s[4 * g + 3] = c3 + b2w;
    }
    __syncthreads();

    float acc = out_b[tid];
#pragma unroll
    for (int j = 0; j < 32; ++j) acc += ctx_s[j] * out_w[tid * 32 + j];
    out[b * 64 + tid] = acc;
}

// ---------------------------------------------------------------------------
extern "C" void kernel_launch(void* const* d_in, const int* in_sizes, int n_in,
                              void* d_out, int out_size, void* d_ws, size_t ws_size,
                              hipStream_t stream)
{
    const int*   seq   = (const int*)  d_in[0];
    const float* embed = (const float*)d_in[1];
    const float* ff1_w = (const float*)d_in[2];
    const float* ff1_b = (const float*)d_in[3];
    const float* ff2_w = (const float*)d_in[4];
    const float* ff2_b = (const float*)d_in[5];
    const float* ln_g  = (const float*)d_in[6];
    const float* ln_b  = (const float*)d_in[7];
    const float* fc1_w = (const float*)d_in[8];
    const float* fc1_b = (const float*)d_in[9];
    const float* fc2_w = (const float*)d_in[10];
    const float* fc2_b = (const float*)d_in[11];
    const float* out_w = (const float*)d_in[12];
    const float* out_b = (const float*)d_in[13];

    float* out = (float*)d_out;
    char* ws = (char*)d_ws;
    float*        table = (float*)(ws + 0);
    float*        G     = (float*)(ws + 8192);
    float*        Z0    = (float*)(ws + 24576);
    float*        wacc  = (float*)(ws + 26624);
    unsigned int* flags = (unsigned int*)(ws + 28672);

    hipMemsetAsync(wacc, 0, sizeof(float), stream);
    hipLaunchKernelGGL(flags_kernel, dim3(256), dim3(256), 0, stream,
                       seq, embed, ff1_w, ff1_b, ff2_w, ff2_b, ln_g, ln_b,
                       fc1_w, table, G, Z0, flags, wacc);
    hipLaunchKernelGGL(scan_kernel, dim3(256), dim3(64), 0, stream,
                       seq, table, G, Z0, fc1_b, fc2_w, fc2_b,
                       out_w, out_b, flags, wacc, out);
}

// Round 16
// 453.289 us; speedup vs baseline: 1.0815x; 1.0815x over previous
//
#include <hip/hip_runtime.h>

#define L_SEQ 4096
#define NSTEP 2047
#define ST_W  (-0.000625f)   // -LR * (2/H) = -0.01/16

typedef float f32x4 __attribute__((ext_vector_type(4)));

// ws layout (bytes):
//  [0,      8192)   table  64x32 f32
//  [8192,  24576)   G      64x64 f32
//  [24576, 26624)   Z0     64x8  f32
//  [26624, 26628)   wacc   f32
//  [28672, 94208)   flags  256 rows x 64 words (bit j of word c = wr_{32c+j})

// ---------------------------------------------------------------------------
// Cross-lane reduction helpers (VALU pipe). Layout: i = lane&7, g = lane>>3.
// ---------------------------------------------------------------------------
__device__ __forceinline__ void redi4(float& a, float& b, float& c, float& d) {
    asm volatile(
        "s_nop 1\n\t"
        "v_add_f32_dpp %0, %0, %0 quad_perm:[1,0,3,2] row_mask:0xf bank_mask:0xf bound_ctrl:0\n\t"
        "v_add_f32_dpp %1, %1, %1 quad_perm:[1,0,3,2] row_mask:0xf bank_mask:0xf bound_ctrl:0\n\t"
        "v_add_f32_dpp %2, %2, %2 quad_perm:[1,0,3,2] row_mask:0xf bank_mask:0xf bound_ctrl:0\n\t"
        "v_add_f32_dpp %3, %3, %3 quad_perm:[1,0,3,2] row_mask:0xf bank_mask:0xf bound_ctrl:0\n\t"
        "v_add_f32_dpp %0, %0, %0 quad_perm:[2,3,0,1] row_mask:0xf bank_mask:0xf bound_ctrl:0\n\t"
        "v_add_f32_dpp %1, %1, %1 quad_perm:[2,3,0,1] row_mask:0xf bank_mask:0xf bound_ctrl:0\n\t"
        "v_add_f32_dpp %2, %2, %2 quad_perm:[2,3,0,1] row_mask:0xf bank_mask:0xf bound_ctrl:0\n\t"
        "v_add_f32_dpp %3, %3, %3 quad_perm:[2,3,0,1] row_mask:0xf bank_mask:0xf bound_ctrl:0\n\t"
        "v_add_f32_dpp %0, %0, %0 row_half_mirror row_mask:0xf bank_mask:0xf bound_ctrl:0\n\t"
        "v_add_f32_dpp %1, %1, %1 row_half_mirror row_mask:0xf bank_mask:0xf bound_ctrl:0\n\t"
        "v_add_f32_dpp %2, %2, %2 row_half_mirror row_mask:0xf bank_mask:0xf bound_ctrl:0\n\t"
        "v_add_f32_dpp %3, %3, %3 row_half_mirror row_mask:0xf bank_mask:0xf bound_ctrl:0"
        : "+v"(a), "+v"(b), "+v"(c), "+v"(d));
}

__device__ __forceinline__ float redg1(float x) {
    float t;
    asm volatile(
        "s_nop 1\n\t"
        "v_add_f32_dpp %0, %0, %0 row_ror:8 row_mask:0xf bank_mask:0xf bound_ctrl:0\n\t"
        "v_mov_b32 %1, %0\n\t"
        "s_nop 1\n\t"
        "v_permlane16_swap_b32 %1, %0\n\t"
        "v_add_f32 %0, %0, %1\n\t"
        "v_mov_b32 %1, %0\n\t"
        "s_nop 1\n\t"
        "v_permlane32_swap_b32 %1, %0\n\t"
        "v_add_f32 %0, %0, %1"
        : "+v"(x), "=&v"(t));
    return x;
}

// select Z[r] among 8 regs; r wave-uniform (SGPR). SALU masks; ONE asm block
// with exactly 7 v_cndmask (single scheduler boundary).
__device__ __forceinline__ float sel8u(const float* Z, int r) {
    unsigned long long m0 = (r & 1) ? ~0ull : 0ull;
    unsigned long long m1 = (r & 2) ? ~0ull : 0ull;
    unsigned long long m2 = (r & 4) ? ~0ull : 0ull;
    float res, t0, t1, t2;
    asm("v_cndmask_b32 %1, %4, %5, %12\n\t"
        "v_cndmask_b32 %2, %6, %7, %12\n\t"
        "v_cndmask_b32 %3, %8, %9, %12\n\t"
        "v_cndmask_b32 %0, %10, %11, %12\n\t"
        "v_cndmask_b32 %1, %1, %2, %13\n\t"
        "v_cndmask_b32 %3, %3, %0, %13\n\t"
        "v_cndmask_b32 %0, %1, %3, %14"
        : "=&v"(res), "=&v"(t0), "=&v"(t1), "=&v"(t2)
        : "v"(Z[0]), "v"(Z[1]), "v"(Z[2]), "v"(Z[3]),
          "v"(Z[4]), "v"(Z[5]), "v"(Z[6]), "v"(Z[7]),
          "s"(m0), "s"(m1), "s"(m2));
    return res;
}

__device__ __forceinline__ float bperm_row(int tok, int i4, float v) {
    int addr = ((tok & 56) << 2) | i4;
    return __int_as_float(__builtin_amdgcn_ds_bpermute(addr, __float_as_int(v)));
}

__device__ __forceinline__ int rli(int x, int l) {
    return __builtin_amdgcn_readlane(x, l);
}

// ---------------------------------------------------------------------------
// Phase A+B1 fused: each block builds table+G in LDS, then its row's gates.
// Block 0 additionally stores table/G/Z0 to ws for the scan kernel.
// ---------------------------------------------------------------------------
__global__ __launch_bounds__(256) void flags_kernel(
    const int* __restrict__ seq, const float* __restrict__ embed,
    const float* __restrict__ ff1_w, const float* __restrict__ ff1_b,
    const float* __restrict__ ff2_w, const float* __restrict__ ff2_b,
    const float* __restrict__ ln_g, const float* __restrict__ ln_b,
    const float* __restrict__ fc1_w,
    float* __restrict__ table, float* __restrict__ G, float* __restrict__ Z0,
    unsigned int* __restrict__ flags, float* __restrict__ wacc)
{
    __shared__ float Gs[4096];
    __shared__ float tl[64][32];
    __shared__ float P[64][64];
    __shared__ int   kt[2048];
    __shared__ float Aa[2048];
    __shared__ float Ws[2048];
    __shared__ float red[256];
    const int tid = threadIdx.x, b = blockIdx.x;
    const int2* sp2 = reinterpret_cast<const int2*>(seq + b * L_SEQ);
    for (int j = tid; j < 2048; j += 256) kt[j] = sp2[j].x;

    if (tid < 64) {
        const int v = tid;
        float h[32], f[32];
#pragma unroll
        for (int j = 0; j < 32; ++j) { h[j] = embed[v * 32 + j]; f[j] = 0.f; }
        for (int k = 0; k < 64; ++k) {
            float z = ff1_b[k];
#pragma unroll
            for (int j = 0; j < 32; ++j) z += h[j] * ff1_w[k * 32 + j];
            z = fmaxf(z, 0.f);
#pragma unroll
            for (int j = 0; j < 32; ++j) f[j] += z * ff2_w[j * 64 + k];
        }
        float x[32], mu = 0.f;
#pragma unroll
        for (int j = 0; j < 32; ++j) { x[j] = h[j] + f[j] + ff2_b[j]; mu += x[j]; }
        mu *= (1.f / 32.f);
        float var = 0.f;
#pragma unroll
        for (int j = 0; j < 32; ++j) { float d = x[j] - mu; var += d * d; }
        var *= (1.f / 32.f);
        const float inv = rsqrtf(var + 1e-5f);
#pragma unroll
        for (int j = 0; j < 32; ++j) {
            float tv = ln_g[j] * (x[j] - mu) * inv + ln_b[j];
            tl[v][j] = tv;
            if (b == 0) table[v * 32 + j] = tv;
        }
    }
    __syncthreads();

    for (int idx = tid; idx < 4096; idx += 256) {
        const int v = idx >> 6, u = idx & 63;
        float acc = 0.f;
#pragma unroll
        for (int j = 0; j < 32; ++j) acc += tl[v][j] * tl[u][j];
        Gs[idx] = acc;
        if (b == 0) G[idx] = acc;
    }
    if (b == 0) {
        for (int idx = tid; idx < 512; idx += 256) {
            const int v = idx >> 3, i = idx & 7;
            float acc = 0.f;
#pragma unroll
            for (int j = 0; j < 32; ++j) acc += fc1_w[i * 32 + j] * tl[v][j];
            Z0[idx] = acc;
        }
    }
    __syncthreads();

    for (int idx = tid; idx < 4096; idx += 256) {
        const int c = idx >> 6, u = idx & 63;
        const int base = c * 32;
        float s = 0.f;
#pragma unroll 4
        for (int j = 0; j < 32; ++j) s += Gs[kt[base + j] * 64 + u];
        P[c][u] = s;
    }
    __syncthreads();
    if (tid < 64) {
        float acc = 0.f;
        for (int c = 0; c < 64; ++c) { float p = P[c][tid]; P[c][tid] = acc; acc += p; }
    }
    __syncthreads();
    for (int t = tid; t < NSTEP; t += 256) {
        const int c = t >> 5, base = c << 5;
        const int ktt = kt[t];
        float a = P[c][ktt];
        for (int s = base; s < t; ++s) a += Gs[kt[s] * 64 + ktt];
        Aa[t] = a;
        Ws[t] = 2.f * a + Gs[ktt * 65];
    }
    __syncthreads();
    float loc[8], tot = 0.f;
    const int base8 = tid * 8;
#pragma unroll
    for (int j = 0; j < 8; ++j) {
        float v = (base8 + j < NSTEP) ? Ws[base8 + j] : 0.f;
        loc[j] = tot; tot += v;
    }
    red[tid] = tot;
    __syncthreads();
    float run = tot;
    for (int off = 1; off < 256; off <<= 1) {
        float add = (tid >= off) ? red[tid - off] : 0.f;
        __syncthreads();
        run += add; red[tid] = run;
        __syncthreads();
    }
    const float excl = run - tot;
    __syncthreads();
#pragma unroll
    for (int j = 0; j < 8; ++j) {
        const int t = base8 + j;
        if (t < NSTEP) {
            const float u_t = excl + loc[j];
            const float tf = (float)t;
            const int ktt = kt[t];
            const float r = fmaf(tf * tf, Gs[ktt * 65] - 16.f, u_t)
                            - 2.f * tf * Aa[t];
            Ws[t] = (t == 0 || r > 0.f) ? 1.f : 0.f;
        }
    }
    __syncthreads();
    int cnt = 0;
    if (tid < 64) {
        unsigned int w = 0;
        for (int j = 0; j < 32; ++j) {
            const int t = tid * 32 + j;
            if (t < NSTEP && Ws[t] != 0.f) w |= 1u << j;
        }
        flags[b * 64 + tid] = w;
        cnt = __popc(w);
    }
    red[tid] = (float)cnt;
    __syncthreads();
    if (tid == 0) {
        float s = 0.f;
        for (int j = 0; j < 64; ++j) s += red[j];
        atomicAdd(wacc, s);
    }
}

// ---------------------------------------------------------------------------
// Phase B2: fast-weight scan. One wave per batch row, 256 blocks (1/CU).
// 2048 steps (last is a flag-0 no-op), outer 64 x fully-unrolled 32.
// Plain-C DS (compiler schedules waits); single-asm sel8u; b1-post fold.
// Best-measured variant (R13: 451 us total / 392 us scan).
// ---------------------------------------------------------------------------
__global__ __launch_bounds__(64) void scan_kernel(
    const int* __restrict__ seq, const float* __restrict__ tableg,
    const float* __restrict__ Gg, const float* __restrict__ Z0g,
    const float* __restrict__ fc1_b, const float* __restrict__ fc2_w,
    const float* __restrict__ fc2_b, const float* __restrict__ out_w,
    const float* __restrict__ out_b, const unsigned int* __restrict__ flags,
    const float* __restrict__ wacc, float* __restrict__ out)
{
    __shared__ float Gs[4096];
    __shared__ float tabs[2048];
    __shared__ float ctx_s[32];
    const int b = blockIdx.x, tid = threadIdx.x;
    const int i = tid & 7, g = tid >> 3;
    const int l31 = tid & 31;
    const int i4 = i << 2;

    if (b == 0 && tid == 0) out[16384] = wacc[0] * (1.0f / 524032.0f);

    for (int idx = tid; idx < 4096; idx += 64) Gs[idx] = Gg[idx];
    for (int idx = tid; idx < 2048; idx += 64) tabs[idx] = tableg[idx];
    __syncthreads();
    const f32x4* tab4 = reinterpret_cast<const f32x4*>(tabs);

    // --- state ---
    float Zr[8];
#pragma unroll
    for (int r = 0; r < 8; ++r) Zr[r] = Z0g[(8 * g + r) * 8 + i];
    float b1 = fc1_b[i];
    float W2r0 = fc2_w[(4 * g + 0) * 8 + i];
    float W2r1 = fc2_w[(4 * g + 1) * 8 + i];
    float W2r2 = fc2_w[(4 * g + 2) * 8 + i];
    float W2r3 = fc2_w[(4 * g + 3) * 8 + i];
    f32x4 b2r = *reinterpret_cast<const f32x4*>(fc2_b + 4 * g);

    const int2* sp2 = reinterpret_cast<const int2*>(seq + b * L_SEQ);
    const unsigned int fwv = flags[b * 64 + tid];   // lane l holds flag word l

    int2 cbA = sp2[l31];          // chunk c
    int2 cbB = sp2[32 + l31];     // chunk c+1
    int2 cbC;                     // chunk c+2 (prefetched per chunk)

    // --- prologue (t = 0) ---
    int kS = rli(cbA.x, 0);
    int vS = rli(cbA.y, 0);
    const f32x4* gp0 = reinterpret_cast<const f32x4*>(Gs + kS * 64 + 8 * g);
    f32x4 GaC = gp0[0], GbC = gp0[1];
    f32x4 vc0 = tab4[vS * 8 + g];
    float yb = bperm_row(kS, i4, sel8u(Zr, kS & 7)) + b1;
    float es0 = b2r.x - vc0.x, es1 = b2r.y - vc0.y;
    float es2 = b2r.z - vc0.z, es3 = b2r.w - vc0.w;
    float c_prev = 0.f, gB1c = 0.f;

    for (int c = 0; c < 64; ++c) {
        const unsigned int fw = (unsigned int)rli((int)fwv, c);
        {   // prefetch chunk c+2 tokens (1 global load / 32 steps)
            int c2 = c + 2; if (c2 > 63) c2 = 63;
            cbC = sp2[c2 * 32 + l31];
        }
#pragma unroll
        for (int j = 0; j < 32; ++j) {
            // token for step t+1 — compile-time lane index
            int kN, vN;
            if (j < 31) { kN = rli(cbA.x, j + 1); vN = rli(cbA.y, j + 1); }
            else        { kN = rli(cbB.x, 0);     vN = rli(cbB.y, 0); }
            const float st = ((fw >> j) & 1u) ? ST_W : 0.f;   // uniform SALU

            // issue ALL DS for step t+1 (plain C; compiler places waits)
            float ynv = bperm_row(kN, i4, sel8u(Zr, kN & 7)); // reads Z_{t-1}
            const f32x4* gpn =
                reinterpret_cast<const f32x4*>(Gs + kN * 64 + 8 * g);
            f32x4 GaN = gpn[0], GbN = gpn[1];
            f32x4 vcN = tab4[vN * 8 + g];
            float gbN = Gs[kS * 64 + kN];        // G[k_t][k_{t+1}]

            // --- critical path (step t) ---
            const float z1 = fmaf(c_prev, gB1c, yb);
            const float a  = fmaxf(z1, 0.f);
            float p0 = W2r0 * a, p1 = W2r1 * a, p2 = W2r2 * a, p3 = W2r3 * a;
            redi4(p0, p1, p2, p3);
            const float dp0 = p0 + es0, dp1 = p1 + es1;
            const float dp2 = p2 + es2, dp3 = p3 + es3;
            float q = redg1(fmaf(W2r0, dp0, W2r1 * dp1) +
                            fmaf(W2r2, dp2, W2r3 * dp3));
            const float cc = (z1 > 0.f) ? st * q : 0.f;

            // --- updates (off critical path) ---
            const float u0 = st * dp0, u1 = st * dp1;
            const float u2 = st * dp2, u3 = st * dp3;
            W2r0 = fmaf(u0, a, W2r0); W2r1 = fmaf(u1, a, W2r1);
            W2r2 = fmaf(u2, a, W2r2); W2r3 = fmaf(u3, a, W2r3);
            b2r.x += u0; b2r.y += u1; b2r.z += u2; b2r.w += u3;
            Zr[0] = fmaf(cc, GaC.x, Zr[0]); Zr[1] = fmaf(cc, GaC.y, Zr[1]);
            Zr[2] = fmaf(cc, GaC.z, Zr[2]); Zr[3] = fmaf(cc, GaC.w, Zr[3]);
            Zr[4] = fmaf(cc, GbC.x, Zr[4]); Zr[5] = fmaf(cc, GbC.y, Zr[5]);
            Zr[6] = fmaf(cc, GbC.z, Zr[6]); Zr[7] = fmaf(cc, GbC.w, Zr[7]);
            b1 += cc;
            // b1-post fold: yb_next = ynv + b1_post; z1_next = fma(cc, gbN, yb)
            const float ybN = ynv + b1;
            es0 = b2r.x - vcN.x; es1 = b2r.y - vcN.y;   // es for step t+1
            es2 = b2r.z - vcN.z; es3 = b2r.w - vcN.w;

            // --- rotate (renamed by unroll) ---
            yb = ybN; c_prev = cc; gB1c = gbN;
            GaC = GaN; GbC = GbN; kS = kN;
        }
        cbA = cbB; cbB = cbC;
    }

    // --- query/context (state = after the 2047 real steps) ---
    const int tq = seq[b * L_SEQ + (L_SEQ - 1)];
    float yq = bperm_row(tq, i4, sel8u(Zr, tq & 7));
    const float zq = yq + b1;
    const float aq = fmaxf(zq, 0.f);
    float c0 = W2r0 * aq, c1 = W2r1 * aq, c2 = W2r2 * aq, c3 = W2r3 * aq;
    redi4(c0, c1, c2, c3);
    if (i == 0) {
        ctx_s[4 * g + 0] = c0 + b2r.x;
        ctx_s[4 * g + 1] = c1 + b2r.y;
        ctx_s[4 * g + 2] = c2 + b2r.z;
        ctx_s[4 * g + 3] = c3 + b2r.w;
    }
    __syncthreads();

    float acc = out_b[tid];
#pragma unroll
    for (int j = 0; j < 32; ++j) acc += ctx_s[j] * out_w[tid * 32 + j];
    out[b * 64 + tid] = acc;
}

// ---------------------------------------------------------------------------
extern "C" void kernel_launch(void* const* d_in, const int* in_sizes, int n_in,
                              void* d_out, int out_size, void* d_ws, size_t ws_size,
                              hipStream_t stream)
{
    const int*   seq   = (const int*)  d_in[0];
    const float* embed = (const float*)d_in[1];
    const float* ff1_w = (const float*)d_in[2];
    const float* ff1_b = (const float*)d_in[3];
    const float* ff2_w = (const float*)d_in[4];
    const float* ff2_b = (const float*)d_in[5];
    const float* ln_g  = (const float*)d_in[6];
    const float* ln_b  = (const float*)d_in[7];
    const float* fc1_w = (const float*)d_in[8];
    const float* fc1_b = (const float*)d_in[9];
    const float* fc2_w = (const float*)d_in[10];
    const float* fc2_b = (const float*)d_in[11];
    const float* out_w = (const float*)d_in[12];
    const float* out_b = (const float*)d_in[13];

    float* out = (float*)d_out;
    char* ws = (char*)d_ws;
    float*        table = (float*)(ws + 0);
    float*        G     = (float*)(ws + 8192);
    float*        Z0    = (float*)(ws + 24576);
    float*        wacc  = (float*)(ws + 26624);
    unsigned int* flags = (unsigned int*)(ws + 28672);

    hipMemsetAsync(wacc, 0, sizeof(float), stream);
    hipLaunchKernelGGL(flags_kernel, dim3(256), dim3(256), 0, stream,
                       seq, embed, ff1_w, ff1_b, ff2_w, ff2_b, ln_g, ln_b,
                       fc1_w, table, G, Z0, flags, wacc);
    hipLaunchKernelGGL(scan_kernel, dim3(256), dim3(64), 0, stream,
                       seq, table, G, Z0, fc1_b, fc2_w, fc2_b,
                       out_w, out_b, flags, wacc, out);
}